// Round 4
// baseline (221.816 us; speedup 1.0000x reference)
//
#include <hip/hip_runtime.h>
#include <hip/hip_bf16.h>

#define EMBED 1536
#define SEQ   896
#define NOUT  5313

#define N0 5313
#define N1 1643
#define N2 128

#define LN_BLOCKS 1792           // 2 rows per block, 4*896 rows
#define GEMM_GRID 1280           // >= worst-case R (1176); surplus blocks do zero-fill
#define BK 64                    // K-tile: 24 iters, double-buffered
#define NKT (EMBED / BK)         // 24

typedef __attribute__((ext_vector_type(8))) short bf16x8;   // 8 bf16 = 4 VGPRs
typedef __attribute__((ext_vector_type(4))) float f32x4;

__device__ __forceinline__ void gload_lds16(const void* g, void* l) {
    __builtin_amdgcn_global_load_lds(
        (const __attribute__((address_space(1))) void*)g,
        (__attribute__((address_space(3))) void*)l, 16, 0, 0);
}

__device__ __forceinline__ int tiles_of(int h) {      // N-tiles of 128
    return (h == 0) ? 42 : (h == 1) ? 13 : (h == 2) ? 1 : 0;
}
__device__ __forceinline__ int nrows_of(int h) {
    return (h == 0) ? N0 : (h == 1) ? N1 : (h == 2) ? N2 : 0;
}

// ---- 1) prep: LN -> bf16 xn ONLY (W-conversion eliminated; B staged from f32 in gemm) ----
__global__ __launch_bounds__(256) void prep_kernel(
    const float* __restrict__ x, const int* __restrict__ head_idx,
    const float* __restrict__ g0, const float* __restrict__ be0,
    const float* __restrict__ g1, const float* __restrict__ be1,
    const float* __restrict__ g2, const float* __restrict__ be2,
    __hip_bfloat16* __restrict__ xn)
{
    const int tid = threadIdx.x;
    // ---- LayerNorm: two rows per block (one per 128-thread half) ----
    const int half = tid >> 7;               // 0 or 1
    const int lt   = tid & 127;
    const int row  = blockIdx.x * 2 + half;  // rows 2i, 2i+1: same batch (896 even)
    const int b    = row / SEQ;
    const int h    = head_idx[b];
    if (h == 3) return;                      // block-uniform: ZeroHead batch, xn unused

    const float* gamma = (h == 1) ? g1 : (h == 2) ? g2 : g0;
    const float* beta  = (h == 1) ? be1 : (h == 2) ? be2 : be0;
    const float* xr = x + (size_t)row * EMBED;

    float4 v[3];
    float sum = 0.f, sq = 0.f;
#pragma unroll
    for (int i = 0; i < 3; ++i) {
        v[i] = ((const float4*)xr)[lt + i * 128];
        sum += v[i].x + v[i].y + v[i].z + v[i].w;
        sq  += v[i].x * v[i].x + v[i].y * v[i].y + v[i].z * v[i].z + v[i].w * v[i].w;
    }
#pragma unroll
    for (int off = 32; off > 0; off >>= 1) {
        sum += __shfl_down(sum, off);
        sq  += __shfl_down(sq, off);
    }
    __shared__ float s_sum[4], s_sq[4];
    const int wave = tid >> 6, lane = tid & 63;
    if (lane == 0) { s_sum[wave] = sum; s_sq[wave] = sq; }
    __syncthreads();
    const int wb = half << 1;
    const float mu  = (s_sum[wb] + s_sum[wb + 1]) * (1.f / EMBED);
    const float var = (s_sq[wb] + s_sq[wb + 1]) * (1.f / EMBED) - mu * mu;
    const float rs  = rsqrtf(var + 1e-5f);

    __hip_bfloat16* xo = xn + (size_t)row * EMBED;
#pragma unroll
    for (int i = 0; i < 3; ++i) {
        const int idx = lt + i * 128;
        float4 gv = ((const float4*)gamma)[idx];
        float4 bv = ((const float4*)beta)[idx];
        union { __hip_bfloat16 h4[4]; short4 s4; } u;
        u.h4[0] = __float2bfloat16((v[i].x - mu) * rs * gv.x + bv.x);
        u.h4[1] = __float2bfloat16((v[i].y - mu) * rs * gv.y + bv.y);
        u.h4[2] = __float2bfloat16((v[i].z - mu) * rs * gv.z + bv.z);
        u.h4[3] = __float2bfloat16((v[i].w - mu) * rs * gv.w + bv.w);
        ((short4*)xo)[idx] = u.s4;
    }
}

// ---- 2) bf16 MFMA GEMM: 128x128 tiles, BK=64 double-buffer.
//      A: gload_lds from xn (bf16). B: reg-staged from f32 W with on-the-fly
//      cvt (T14 issue-early / write-late) — kills the prep W pass + wpad trip.
//      mt FASTEST: XCD chunk shares the B panel (L2) + batch A panels fit L2.
__global__ __launch_bounds__(256, 2) void head_gemm(
    const __hip_bfloat16* __restrict__ xn,   // (4*896, 1536)
    const float* __restrict__ W0f, const float* __restrict__ W1f,
    const float* __restrict__ W2f,
    const float* __restrict__ b0, const float* __restrict__ b1,
    const float* __restrict__ b2,
    const int* __restrict__ head_idx,
    float* __restrict__ out)                 // (4, 896, 5313)
{
    const int h0 = head_idx[0], h1 = head_idx[1];
    const int h2 = head_idx[2], h3 = head_idx[3];
    const int t0 = tiles_of(h0) * 7, t1 = tiles_of(h1) * 7;
    const int t2 = tiles_of(h2) * 7, t3 = tiles_of(h3) * 7;
    const int R = t0 + t1 + t2 + t3;
    const int tid = threadIdx.x;

    if ((int)blockIdx.x >= R) {
        // ---- zero-fill: strided rows over the invalid column ranges ----
        const int j = blockIdx.x - R;
        const int ZB = GEMM_GRID - R;            // >=104 whenever zf is needed
        for (int row = j; row < 4 * SEQ; row += ZB) {
            const int b = row / SEQ;
            const int h = (b == 0) ? h0 : (b == 1) ? h1 : (b == 2) ? h2 : h3;
            const int n = nrows_of(h);
            if (n >= NOUT) continue;
            float* o = out + (size_t)row * NOUT;
            const int pre0 = (4 - (int)(((size_t)row * NOUT + n) & 3)) & 3;
            const int pre_end = min(n + pre0, NOUT);
            for (int c = n + tid; c < pre_end; c += 256) o[c] = 0.f;
            const int nvec = (NOUT - pre_end) >> 2;
            const float4 z = make_float4(0.f, 0.f, 0.f, 0.f);
            float4* ov = (float4*)(o + pre_end);
            for (int i = tid; i < nvec; i += 256) ov[i] = z;
            for (int c = pre_end + (nvec << 2) + tid; c < NOUT; c += 256) o[c] = 0.f;
        }
        return;
    }

    // ---- T1: bijective XCD-chunked remap (m204) over the R real tiles.
    const int q = R >> 3, r7 = R & 7;
    const int xcd = (int)blockIdx.x & 7, jx = (int)blockIdx.x >> 3;
    const int tile = (xcd < r7 ? xcd * (q + 1) : r7 * (q + 1) + (xcd - r7) * q) + jx;

    int rem = tile, b;
    if (rem < t0)                { b = 0; }
    else if (rem < t0 + t1)      { b = 1; rem -= t0; }
    else if (rem < t0 + t1 + t2) { b = 2; rem -= t0 + t1; }
    else                         { b = 3; rem -= t0 + t1 + t2; }

    const int h = (b == 0) ? h0 : (b == 1) ? h1 : (b == 2) ? h2 : h3;
    const int nt = rem / 7;                      // N-tile (slow): B panel shared
    const int mt = rem - nt * 7;                 // M-tile FASTEST (0..6)
    const int nrows = nrows_of(h);
    const float* Wf = (h == 1) ? W1f : (h == 2) ? W2f : W0f;

    const int col0 = nt * 128;
    float* outb = out + ((size_t)b * SEQ + (size_t)mt * 128) * NOUT;

    // double-buffered K-tiles: 2 x (16+16) KB = 64 KB -> 2 blocks/CU
    __shared__ __hip_bfloat16 As[2][128 * BK];
    __shared__ __hip_bfloat16 Bs[2][128 * BK];
    const __hip_bfloat16* Ab = xn + ((size_t)b * SEQ + (size_t)mt * 128) * EMBED;

    const int wave = tid >> 6, lane = tid & 63;
    const int wm = wave >> 1, wn = wave & 1;         // 2x2 waves of 64x64
    const int fm = lane & 15, quad = lane >> 4;

    // A: async global->LDS, source-swizzled, linear LDS dest (proven path)
    auto stageA = [&](int buf, int kt) {
        const int k0 = kt * BK;
#pragma unroll
        for (int i = 0; i < 4; ++i) {                // 1024 16B chunks
            const int c = tid + i * 256;
            const int arow = c >> 3;                 // 8 chunks per 64-col row
            const int kc = (c & 7) ^ (arow & 7);     // xor-swizzled k-chunk
            gload_lds16(Ab + (size_t)arow * EMBED + k0 + kc * 8, &As[buf][c * 8]);
        }
    };

    // B: reg-staged f32 -> bf16. Same (row,kchunk)->LDS mapping as A, so the
    // unchanged read path sees an identical swizzle (both-sides rule).
    float4 bld[4][2];
    auto stageB_load = [&](int kt) {
        const int k0 = kt * BK;
#pragma unroll
        for (int r = 0; r < 4; ++r) {
            const int c = tid + r * 256;
            const int brow = c >> 3;
            const int kc = (c & 7) ^ (brow & 7);
            const int w = col0 + brow;
            if (w < nrows) {
                const float4* src = (const float4*)(Wf + (size_t)w * EMBED + k0 + kc * 8);
                bld[r][0] = src[0];
                bld[r][1] = src[1];
            } else {
                bld[r][0] = make_float4(0.f, 0.f, 0.f, 0.f);
                bld[r][1] = make_float4(0.f, 0.f, 0.f, 0.f);
            }
        }
    };
    auto stageB_write = [&](int buf) {
#pragma unroll
        for (int r = 0; r < 4; ++r) {
            const int c = tid + r * 256;
            union { __hip_bfloat16 h8[8]; int4 v4; } u;
            u.h8[0] = __float2bfloat16(bld[r][0].x);
            u.h8[1] = __float2bfloat16(bld[r][0].y);
            u.h8[2] = __float2bfloat16(bld[r][0].z);
            u.h8[3] = __float2bfloat16(bld[r][0].w);
            u.h8[4] = __float2bfloat16(bld[r][1].x);
            u.h8[5] = __float2bfloat16(bld[r][1].y);
            u.h8[6] = __float2bfloat16(bld[r][1].z);
            u.h8[7] = __float2bfloat16(bld[r][1].w);
            *(int4*)&Bs[buf][c * 8] = u.v4;          // ds_write_b128
        }
    };

    f32x4 acc[4][4] = {};

    // prologue: fill buffer 0
    stageB_load(0);
    stageA(0, 0);
    stageB_write(0);
    __syncthreads();                                 // drains vmcnt+lgkmcnt

    for (int kt = 0; kt < NKT; ++kt) {               // 24 iterations
        const int cur = kt & 1;
        const bool more = (kt + 1 < NKT);
        if (more) {
            stageB_load(kt + 1);                     // issue f32 loads early
            stageA(cur ^ 1, kt + 1);                 // async A for next tile
        }
#pragma unroll
        for (int ks = 0; ks < 2; ++ks) {             // 2 x K32 sub-steps
            bf16x8 af[4], bfr[4];
#pragma unroll
            for (int i = 0; i < 4; ++i)
                af[i] = *(const bf16x8*)&As[cur][(wm * 64 + i * 16 + fm) * BK +
                                                ((((ks << 2) + quad)) ^ (fm & 7)) * 8];
#pragma unroll
            for (int j2 = 0; j2 < 4; ++j2)
                bfr[j2] = *(const bf16x8*)&Bs[cur][(wn * 64 + j2 * 16 + fm) * BK +
                                                  ((((ks << 2) + quad)) ^ (fm & 7)) * 8];
#pragma unroll
            for (int i = 0; i < 4; ++i)
#pragma unroll
                for (int j2 = 0; j2 < 4; ++j2)
                    acc[i][j2] = __builtin_amdgcn_mfma_f32_16x16x32_bf16(
                        af[i], bfr[j2], acc[i][j2], 0, 0, 0);
        }
        if (more) stageB_write(cur ^ 1);             // cvt+ds_write after compute
        __syncthreads();                             // readers done + stages landed
    }

    // epilogue: bias + softplus; store ONLY valid cols (zero region owned by zf)
    const float* bias = (h == 1) ? b1 : (h == 2) ? b2 : b0;
#pragma unroll
    for (int j = 0; j < 4; ++j) {
        const int lcol = col0 + wn * 64 + j * 16 + fm;
        const bool valid = lcol < nrows;
        const float bv = valid ? bias[lcol] : 0.f;
#pragma unroll
        for (int i = 0; i < 4; ++i) {
            const int rbase = wm * 64 + i * 16 + quad * 4;
#pragma unroll
            for (int r = 0; r < 4; ++r) {
                const float v = acc[i][j][r] + bv;
                // softplus: max(v,0) + log(1 + exp(-|v|)) — overflow-safe
                const float sp = fmaxf(v, 0.f) + __logf(1.f + __expf(-fabsf(v)));
                if (valid) outb[(size_t)(rbase + r) * NOUT + lcol] = sp;
            }
        }
    }
}

extern "C" void kernel_launch(void* const* d_in, const int* in_sizes, int n_in,
                              void* d_out, int out_size, void* d_ws, size_t ws_size,
                              hipStream_t stream) {
    const float* x   = (const float*)d_in[0];
    const int* hidx  = (const int*)d_in[1];
    const float* g0  = (const float*)d_in[2];
    const float* be0 = (const float*)d_in[3];
    const float* W0  = (const float*)d_in[4];
    const float* b0  = (const float*)d_in[5];
    const float* g1  = (const float*)d_in[6];
    const float* be1 = (const float*)d_in[7];
    const float* W1  = (const float*)d_in[8];
    const float* b1  = (const float*)d_in[9];
    const float* g2  = (const float*)d_in[10];
    const float* be2 = (const float*)d_in[11];
    const float* W2  = (const float*)d_in[12];
    const float* b2  = (const float*)d_in[13];
    float* out = (float*)d_out;

    // workspace: xn only (wpad eliminated)
    __hip_bfloat16* xn = (__hip_bfloat16*)d_ws;

    prep_kernel<<<LN_BLOCKS, 256, 0, stream>>>(
        x, hidx, g0, be0, g1, be1, g2, be2, xn);
    head_gemm<<<GEMM_GRID, 256, 0, stream>>>(
        xn, W0, W1, W2, b0, b1, b2, hidx, out);
}

// Round 5
// 193.239 us; speedup vs baseline: 1.1479x; 1.1479x over previous
//
#include <hip/hip_runtime.h>
#include <hip/hip_bf16.h>

#define EMBED 1536
#define SEQ   896
#define NOUT  5313

#define N0 5313
#define N1 1643
#define N2 128

#define LN_BLOCKS 1792           // 2 rows per block, 4*896 rows
#define GEMM_GRID 1280           // >= worst-case R (1176); surplus blocks do zero-fill
#define BK 64                    // K-tile: 24 iters, double-buffered
#define NKT (EMBED / BK)         // 24

typedef __attribute__((ext_vector_type(8))) short bf16x8;   // 8 bf16 = 4 VGPRs
typedef __attribute__((ext_vector_type(4))) float f32x4;

__device__ __forceinline__ void gload_lds16(const void* g, void* l) {
    __builtin_amdgcn_global_load_lds(
        (const __attribute__((address_space(1))) void*)g,
        (__attribute__((address_space(3))) void*)l, 16, 0, 0);
}

__device__ __forceinline__ int tiles_of(int h) {      // N-tiles of 128
    return (h == 0) ? 42 : (h == 1) ? 13 : (h == 2) ? 1 : 0;
}
__device__ __forceinline__ int nrows_of(int h) {
    return (h == 0) ? N0 : (h == 1) ? N1 : (h == 2) ? N2 : 0;
}

// ---- 1) prep: LN -> bf16 xn ONLY ----
__global__ __launch_bounds__(256) void prep_kernel(
    const float* __restrict__ x, const int* __restrict__ head_idx,
    const float* __restrict__ g0, const float* __restrict__ be0,
    const float* __restrict__ g1, const float* __restrict__ be1,
    const float* __restrict__ g2, const float* __restrict__ be2,
    __hip_bfloat16* __restrict__ xn)
{
    const int tid = threadIdx.x;
    const int half = tid >> 7;               // 0 or 1
    const int lt   = tid & 127;
    const int row  = blockIdx.x * 2 + half;  // rows 2i, 2i+1: same batch (896 even)
    const int b    = row / SEQ;
    const int h    = head_idx[b];
    if (h == 3) return;                      // block-uniform: ZeroHead batch, xn unused

    const float* gamma = (h == 1) ? g1 : (h == 2) ? g2 : g0;
    const float* beta  = (h == 1) ? be1 : (h == 2) ? be2 : be0;
    const float* xr = x + (size_t)row * EMBED;

    float4 v[3];
    float sum = 0.f, sq = 0.f;
#pragma unroll
    for (int i = 0; i < 3; ++i) {
        v[i] = ((const float4*)xr)[lt + i * 128];
        sum += v[i].x + v[i].y + v[i].z + v[i].w;
        sq  += v[i].x * v[i].x + v[i].y * v[i].y + v[i].z * v[i].z + v[i].w * v[i].w;
    }
#pragma unroll
    for (int off = 32; off > 0; off >>= 1) {
        sum += __shfl_down(sum, off);
        sq  += __shfl_down(sq, off);
    }
    __shared__ float s_sum[4], s_sq[4];
    const int wave = tid >> 6, lane = tid & 63;
    if (lane == 0) { s_sum[wave] = sum; s_sq[wave] = sq; }
    __syncthreads();
    const int wb = half << 1;
    const float mu  = (s_sum[wb] + s_sum[wb + 1]) * (1.f / EMBED);
    const float var = (s_sq[wb] + s_sq[wb + 1]) * (1.f / EMBED) - mu * mu;
    const float rs  = rsqrtf(var + 1e-5f);

    __hip_bfloat16* xo = xn + (size_t)row * EMBED;
#pragma unroll
    for (int i = 0; i < 3; ++i) {
        const int idx = lt + i * 128;
        float4 gv = ((const float4*)gamma)[idx];
        float4 bv = ((const float4*)beta)[idx];
        union { __hip_bfloat16 h4[4]; short4 s4; } u;
        u.h4[0] = __float2bfloat16((v[i].x - mu) * rs * gv.x + bv.x);
        u.h4[1] = __float2bfloat16((v[i].y - mu) * rs * gv.y + bv.y);
        u.h4[2] = __float2bfloat16((v[i].z - mu) * rs * gv.z + bv.z);
        u.h4[3] = __float2bfloat16((v[i].w - mu) * rs * gv.w + bv.w);
        ((short4*)xo)[idx] = u.s4;
    }
}

// ---- 2) bf16 MFMA GEMM: 128x128 tiles, BK=64, mt-fastest XCD chunks.
//      A: gload_lds double-buffer (counted vmcnt, depth 2).
//      B: f32 W reg-staged with TWO register sets — loads for tile kt+2
//      issued at TOP of iter kt (2 compute phases of lead), cvt+ds_write of
//      tile kt+1 at BOTTOM of iter kt. No full vmcnt drains in the loop.
__global__ __launch_bounds__(256, 2) void head_gemm(
    const __hip_bfloat16* __restrict__ xn,   // (4*896, 1536)
    const float* __restrict__ W0f, const float* __restrict__ W1f,
    const float* __restrict__ W2f,
    const float* __restrict__ b0, const float* __restrict__ b1,
    const float* __restrict__ b2,
    const int* __restrict__ head_idx,
    float* __restrict__ out)                 // (4, 896, 5313)
{
    const int h0 = head_idx[0], h1 = head_idx[1];
    const int h2 = head_idx[2], h3 = head_idx[3];
    const int t0 = tiles_of(h0) * 7, t1 = tiles_of(h1) * 7;
    const int t2 = tiles_of(h2) * 7, t3 = tiles_of(h3) * 7;
    const int R = t0 + t1 + t2 + t3;
    const int tid = threadIdx.x;

    if ((int)blockIdx.x >= R) {
        // ---- zero-fill: strided rows over the invalid column ranges ----
        const int j = blockIdx.x - R;
        const int ZB = GEMM_GRID - R;            // >=104 whenever zf is needed
        for (int row = j; row < 4 * SEQ; row += ZB) {
            const int b = row / SEQ;
            const int h = (b == 0) ? h0 : (b == 1) ? h1 : (b == 2) ? h2 : h3;
            const int n = nrows_of(h);
            if (n >= NOUT) continue;
            float* o = out + (size_t)row * NOUT;
            const int pre0 = (4 - (int)(((size_t)row * NOUT + n) & 3)) & 3;
            const int pre_end = min(n + pre0, NOUT);
            for (int c = n + tid; c < pre_end; c += 256) o[c] = 0.f;
            const int nvec = (NOUT - pre_end) >> 2;
            const float4 z = make_float4(0.f, 0.f, 0.f, 0.f);
            float4* ov = (float4*)(o + pre_end);
            for (int i = tid; i < nvec; i += 256) ov[i] = z;
            for (int c = pre_end + (nvec << 2) + tid; c < NOUT; c += 256) o[c] = 0.f;
        }
        return;
    }

    // ---- T1: bijective XCD-chunked remap (m204) over the R real tiles.
    const int q = R >> 3, r7 = R & 7;
    const int xcd = (int)blockIdx.x & 7, jx = (int)blockIdx.x >> 3;
    const int tile = (xcd < r7 ? xcd * (q + 1) : r7 * (q + 1) + (xcd - r7) * q) + jx;

    int rem = tile, b;
    if (rem < t0)                { b = 0; }
    else if (rem < t0 + t1)      { b = 1; rem -= t0; }
    else if (rem < t0 + t1 + t2) { b = 2; rem -= t0 + t1; }
    else                         { b = 3; rem -= t0 + t1 + t2; }

    const int h = (b == 0) ? h0 : (b == 1) ? h1 : (b == 2) ? h2 : h3;
    const int nt = rem / 7;                      // N-tile (slow): B panel shared on XCD
    const int mt = rem - nt * 7;                 // M-tile FASTEST (0..6)
    const int nrows = nrows_of(h);
    const float* Wf = (h == 1) ? W1f : (h == 2) ? W2f : W0f;

    const int col0 = nt * 128;
    float* outb = out + ((size_t)b * SEQ + (size_t)mt * 128) * NOUT;

    // double-buffered K-tiles: 2 x (16+16) KB = 64 KB -> 2 blocks/CU
    __shared__ __hip_bfloat16 As[2][128 * BK];
    __shared__ __hip_bfloat16 Bs[2][128 * BK];
    const __hip_bfloat16* Ab = xn + ((size_t)b * SEQ + (size_t)mt * 128) * EMBED;

    const int wave = tid >> 6, lane = tid & 63;
    const int wm = wave >> 1, wn = wave & 1;         // 2x2 waves of 64x64
    const int fm = lane & 15, quad = lane >> 4;

    // A: async global->LDS, source-swizzled, linear LDS dest (proven path)
    auto stageA = [&](int buf, int kt) {
        const int k0 = kt * BK;
#pragma unroll
        for (int i = 0; i < 4; ++i) {                // 1024 16B chunks
            const int c = tid + i * 256;
            const int arow = c >> 3;                 // 8 chunks per 64-col row
            const int kc = (c & 7) ^ (arow & 7);     // xor-swizzled k-chunk
            gload_lds16(Ab + (size_t)arow * EMBED + k0 + kc * 8, &As[buf][c * 8]);
        }
    };

    // B register sets: static-indexed (named arrays, rule #20)
    float4 bset0[4][2], bset1[4][2];

    auto bload = [&](float4 (&s)[4][2], int kt) {    // 8 f32x4 loads
        const int k0 = kt * BK;
#pragma unroll
        for (int r = 0; r < 4; ++r) {
            const int c = tid + r * 256;
            const int brow = c >> 3;
            const int kc = (c & 7) ^ (brow & 7);     // same swizzle as read path
            const int w = col0 + brow;
            if (w < nrows) {
                const float4* src = (const float4*)(Wf + (size_t)w * EMBED + k0 + kc * 8);
                s[r][0] = src[0];
                s[r][1] = src[1];
            } else {
                s[r][0] = make_float4(0.f, 0.f, 0.f, 0.f);
                s[r][1] = make_float4(0.f, 0.f, 0.f, 0.f);
            }
        }
    };
    auto bwrite = [&](float4 (&s)[4][2], int buf) {  // cvt + ds_write_b128
#pragma unroll
        for (int r = 0; r < 4; ++r) {
            const int c = tid + r * 256;
            union { __hip_bfloat16 h8[8]; int4 v4; } u;
            u.h8[0] = __float2bfloat16(s[r][0].x);
            u.h8[1] = __float2bfloat16(s[r][0].y);
            u.h8[2] = __float2bfloat16(s[r][0].z);
            u.h8[3] = __float2bfloat16(s[r][0].w);
            u.h8[4] = __float2bfloat16(s[r][1].x);
            u.h8[5] = __float2bfloat16(s[r][1].y);
            u.h8[6] = __float2bfloat16(s[r][1].z);
            u.h8[7] = __float2bfloat16(s[r][1].w);
            *(int4*)&Bs[buf][c * 8] = u.v4;
        }
    };

    f32x4 acc[4][4] = {};

    auto compute = [&](int cur) {
#pragma unroll
        for (int ks = 0; ks < 2; ++ks) {             // 2 x K32 sub-steps
            bf16x8 af[4], bfr[4];
#pragma unroll
            for (int i = 0; i < 4; ++i)
                af[i] = *(const bf16x8*)&As[cur][(wm * 64 + i * 16 + fm) * BK +
                                                ((((ks << 2) + quad)) ^ (fm & 7)) * 8];
#pragma unroll
            for (int j2 = 0; j2 < 4; ++j2)
                bfr[j2] = *(const bf16x8*)&Bs[cur][(wn * 64 + j2 * 16 + fm) * BK +
                                                  ((((ks << 2) + quad)) ^ (fm & 7)) * 8];
#pragma unroll
            for (int i = 0; i < 4; ++i)
#pragma unroll
                for (int j2 = 0; j2 < 4; ++j2)
                    acc[i][j2] = __builtin_amdgcn_mfma_f32_16x16x32_bf16(
                        af[i], bfr[j2], acc[i][j2], 0, 0, 0);
        }
    };

    // prologue: tiles 0 and 1 in flight; B(0) written to LDS
    bload(bset0, 0);                                 // 8 loads
    bload(bset1, 1);                                 // 8 loads
    stageA(0, 0);                                    // 4 gload_lds
    stageA(1, 1);                                    // 4 gload_lds
    bwrite(bset0, 0);                                // compiler waits bset0 regs only

    // per-iteration body. FIFO at the wait point of iter kt (after t0):
    //   A(kt):4, bld(kt+1):8, A(kt+1):4, bld(kt+2):8  -> vmcnt(12) retires
    //   A(kt) AND bld(kt+1) (both consumed this iteration). Last iter: drain.
#define GEMM_ITER(KT, CUR, SETC, SETN)                                        \
    {                                                                         \
        const int kt = (KT);                                                  \
        if (kt + 2 < NKT) bload(SETC, kt + 2);          /* t0: issue early */ \
        if (kt == NKT - 1) asm volatile("s_waitcnt vmcnt(0)" ::: "memory");   \
        else               asm volatile("s_waitcnt vmcnt(12)" ::: "memory");  \
        asm volatile("s_waitcnt lgkmcnt(0)" ::: "memory"); /* B writes in */  \
        __builtin_amdgcn_s_barrier();                                         \
        compute(CUR);                                                         \
        __builtin_amdgcn_s_barrier();                   /* readers done */    \
        if (kt + 2 < NKT) stageA(CUR, kt + 2);          /* A into freed buf */\
        if (kt + 1 < NKT) bwrite(SETN, CUR ^ 1);        /* B(kt+1) to LDS */  \
    }

    for (int kt2 = 0; kt2 < NKT; kt2 += 2) {             // NKT = 24 (even)
        GEMM_ITER(kt2,     0, bset0, bset1);
        GEMM_ITER(kt2 + 1, 1, bset1, bset0);
    }
#undef GEMM_ITER

    // epilogue: bias + softplus; store ONLY valid cols (zero region owned by zf)
    const float* bias = (h == 1) ? b1 : (h == 2) ? b2 : b0;
#pragma unroll
    for (int j = 0; j < 4; ++j) {
        const int lcol = col0 + wn * 64 + j * 16 + fm;
        const bool valid = lcol < nrows;
        const float bv = valid ? bias[lcol] : 0.f;
#pragma unroll
        for (int i = 0; i < 4; ++i) {
            const int rbase = wm * 64 + i * 16 + quad * 4;
#pragma unroll
            for (int r = 0; r < 4; ++r) {
                const float v = acc[i][j][r] + bv;
                // softplus: max(v,0) + log(1 + exp(-|v|)) — overflow-safe
                const float sp = fmaxf(v, 0.f) + __logf(1.f + __expf(-fabsf(v)));
                if (valid) outb[(size_t)(rbase + r) * NOUT + lcol] = sp;
            }
        }
    }
}

extern "C" void kernel_launch(void* const* d_in, const int* in_sizes, int n_in,
                              void* d_out, int out_size, void* d_ws, size_t ws_size,
                              hipStream_t stream) {
    const float* x   = (const float*)d_in[0];
    const int* hidx  = (const int*)d_in[1];
    const float* g0  = (const float*)d_in[2];
    const float* be0 = (const float*)d_in[3];
    const float* W0  = (const float*)d_in[4];
    const float* b0  = (const float*)d_in[5];
    const float* g1  = (const float*)d_in[6];
    const float* be1 = (const float*)d_in[7];
    const float* W1  = (const float*)d_in[8];
    const float* b1  = (const float*)d_in[9];
    const float* g2  = (const float*)d_in[10];
    const float* be2 = (const float*)d_in[11];
    const float* W2  = (const float*)d_in[12];
    const float* b2  = (const float*)d_in[13];
    float* out = (float*)d_out;

    // workspace: xn only (wpad eliminated)
    __hip_bfloat16* xn = (__hip_bfloat16*)d_ws;

    prep_kernel<<<LN_BLOCKS, 256, 0, stream>>>(
        x, hidx, g0, be0, g1, be1, g2, be2, xn);
    head_gemm<<<GEMM_GRID, 256, 0, stream>>>(
        xn, W0, W1, W2, b0, b1, b2, hidx, out);
}